// Round 13
// baseline (1458.915 us; speedup 1.0000x reference)
//
#include <hip/hip_runtime.h>
#include <hip/hip_fp16.h>
#include <cstdint>
#include <cstddef>

// Problem constants: B=256, C=1, NMAX=256 -> N=65536 nodes, E=N*16=1048576,
// EMB=HID=128, decode K = NMAX = 256. Bucket b (= dst>>8) == graph b.
#define NN   65536
#define NE   1048576
#define FD   128
#define KDEC 256
#define NGRAPH 256
#define EPB  4096                // edges per binning block
#define BCAP 4608                // per-bucket record capacity (mean 4096 + 8 sigma)

typedef __attribute__((ext_vector_type(8))) short s16x8;
typedef __attribute__((ext_vector_type(4))) float f32x4;

__device__ __forceinline__ ushort f2bf(float x) {
  uint u = __float_as_uint(x);
  uint r = (u + 0x7fffu + ((u >> 16) & 1u)) >> 16;  // RNE
  return (ushort)r;
}
__device__ __forceinline__ float bf2f(ushort h) {
  return __uint_as_float(((uint)h) << 16);
}

// ---------------- edge binning: radix-partition into per-bucket chunks --------
// 256 blocks (1024 thr): 4096 edges each. LDS count -> scan -> LDS-sorted
// placement -> coalesced streamed write into each bucket's binbuf chunk.
// Record: (dlow<<16) | src  (bucket in bits 24-31 during sort, masked at write).

__global__ __launch_bounds__(1024) void k_histbin(const int* __restrict__ edges,
                                                  uint* __restrict__ binbuf,
                                                  int* __restrict__ gbin) {
  const int b = blockIdx.x, t = threadIdx.x;
  __shared__ int lcnt[256];
  __shared__ int lsum[256];   // inclusive prefix of lcnt
  __shared__ int gbase[256];
  __shared__ uint sorted[EPB];

  if (t < 256) lcnt[t] = 0;
  __syncthreads();

  uint rec[4];
  ushort bkt[4], lidx[4];
#pragma unroll
  for (int r = 0; r < 4; r++) {
    int i = b * EPB + r * 1024 + t;
    int2 e = ((const int2*)edges)[i];
    int bucket = e.y >> 8;
    int li = atomicAdd(&lcnt[bucket], 1);
    rec[r] = ((uint)bucket << 24) | ((uint)(e.y & 255) << 16) | (uint)e.x;
    bkt[r] = (ushort)bucket;
    lidx[r] = (ushort)li;
  }
  __syncthreads();

  if (t < 256) lsum[t] = lcnt[t];
  __syncthreads();
  for (int off = 1; off < 256; off <<= 1) {
    int v = 0;
    if (t < 256 && t >= off) v = lsum[t - off];
    __syncthreads();
    if (t < 256) lsum[t] += v;
    __syncthreads();
  }
  if (t < 256) gbase[t] = atomicAdd(&gbin[t], lcnt[t]);
  __syncthreads();

#pragma unroll
  for (int r = 0; r < 4; r++) {
    int B = bkt[r];
    sorted[lsum[B] - lcnt[B] + lidx[r]] = rec[r];
  }
  __syncthreads();

  for (int s = t; s < EPB; s += 1024) {
    uint v = sorted[s];
    int B = v >> 24;
    int ex = lsum[B] - lcnt[B];
    binbuf[B * BCAP + gbase[B] + (s - ex)] = v & 0xFFFFFFu;  // (dlow<<16)|src
  }
}

// ---------------- misc: dinv + W-fuse(+split) + W2 prep, one dispatch ----------
// blocks 0-255: bucket-local degree count (LDS) -> dinv (no global atomics).
// blocks 256-383: Wfused = Wdec@Wc1, written DIRECTLY as split bf16 frag-major
//                 planes (+bfused = bdec@Wc1).
// blocks 384-447: prep Wc2 -> split frag-major planes.
// frag dst(k,c) = ((k/32)*8 + c/16)*512 + ((c&15) + 16*((k&31)>>3))*8 + (k&7)

__device__ __forceinline__ void wsplit(float w, int k, int c,
                                       ushort* __restrict__ H,
                                       ushort* __restrict__ L) {
  ushort h = f2bf(w);
  size_t dst = ((size_t)((k >> 5) * 8 + (c >> 4)) * 64 +
                (size_t)((c & 15) + 16 * ((k & 31) >> 3))) * 8 + (k & 7);
  H[dst] = h;
  L[dst] = f2bf(w - bf2f(h));
}

__global__ __launch_bounds__(256) void k_misc1(const uint* __restrict__ binbuf,
                                               const int* __restrict__ gbin,
                                               float* __restrict__ dinv,
                                               const float* __restrict__ Wdec,
                                               const float* __restrict__ Wc1,
                                               const float* __restrict__ bdec,
                                               float* __restrict__ bfused,
                                               ushort* __restrict__ wfh,
                                               ushort* __restrict__ wfl,
                                               const float* __restrict__ Wc2,
                                               ushort* __restrict__ w2h,
                                               ushort* __restrict__ w2l) {
  int b = blockIdx.x, t = threadIdx.x;
  if (b < 256) {
    __shared__ int lc[256];
    lc[t] = 0;
    __syncthreads();
    int m = gbin[b];
    for (int i = t; i < m; i += 256)
      atomicAdd(&lc[(binbuf[b * BCAP + i] >> 16) & 0xFF], 1);
    __syncthreads();
    dinv[b * 256 + t] = rsqrtf((float)(lc[t] + 1));
  } else if (b < 384) {
    int i = (b - 256) * 256 + t;  // 0..32767
    int k = i >> 7, c = i & 127;
    float acc = 0.f;
#pragma unroll 8
    for (int j = 0; j < 128; j++) acc = fmaf(Wdec[k * FD + j], Wc1[j * FD + c], acc);
    wsplit(acc, k, c, wfh, wfl);
    if (b == 256 && t < 128) {
      float ba = 0.f;
      for (int j = 0; j < 128; j++) ba = fmaf(bdec[j], Wc1[j * FD + t], ba);
      bfused[t] = ba;
    }
  } else {
    int i = (b - 384) * 256 + t;  // 0..16383
    wsplit(Wc2[i], i >> 7, i & 127, w2h, w2l);
  }
}

// ---------------- split-bf16 MFMA GEMM, LDS-B double-buffered pipeline ----------
// (unchanged from round 12 — proven) 256 thr = 4 waves; wave owns 32 rows;
// BM=128. B staged once per block per K-step into double-buffered LDS; A
// prefetched one K-step ahead. Output row-major bf16, row-scaled by scale[].

template <bool ASPLIT>
__global__ __launch_bounds__(256) void k_gemm(const void* __restrict__ A0,
                                              const void* __restrict__ A1,
                                              const ushort* __restrict__ Whi,
                                              const ushort* __restrict__ Wlo,
                                              const float* __restrict__ bias,
                                              const float* __restrict__ scale,
                                              ushort* __restrict__ Y, int K) {
  __shared__ ushort Bs[2][8192];  // [buf][hi 4096 | lo 4096] = 32 KB
  const int t = threadIdx.x;
  const int w = t >> 6;
  const int l = t & 63;
  const int lr = l & 15;
  const int kg = l >> 4;
  const int r0 = blockIdx.x * 128 + w * 32;
  const int nks = K >> 5;

  f32x4 acc[2][8];
#pragma unroll
  for (int mb = 0; mb < 2; mb++)
#pragma unroll
    for (int nb = 0; nb < 8; nb++) acc[mb][nb] = (f32x4)0.f;

  f32x4 araw[4];
  s16x8 ahn[2], aln[2];
  s16x8 bh0, bh1, bl0, bl1;

  auto issueA = [&](int s) {
#pragma unroll
    for (int mb = 0; mb < 2; mb++) {
      size_t base = (size_t)(r0 + mb * 16 + lr) * K + s * 32 + kg * 8;
      if (ASPLIT) {
        ahn[mb] = *(const s16x8*)((const ushort*)A0 + base);
        aln[mb] = *(const s16x8*)((const ushort*)A1 + base);
      } else {
        const float* xp = (const float*)A0 + base;
        araw[mb * 2] = *(const f32x4*)xp;
        araw[mb * 2 + 1] = *(const f32x4*)(xp + 4);
      }
    }
  };
  auto issueB = [&](int s) {
    const ushort* ph = Whi + (size_t)s * 4096 + t * 16;
    const ushort* pl = Wlo + (size_t)s * 4096 + t * 16;
    bh0 = *(const s16x8*)ph;
    bh1 = *(const s16x8*)(ph + 8);
    bl0 = *(const s16x8*)pl;
    bl1 = *(const s16x8*)(pl + 8);
  };
  auto writeB = [&](int buf) {
    *(s16x8*)&Bs[buf][t * 16] = bh0;
    *(s16x8*)&Bs[buf][t * 16 + 8] = bh1;
    *(s16x8*)&Bs[buf][4096 + t * 16] = bl0;
    *(s16x8*)&Bs[buf][4096 + t * 16 + 8] = bl1;
  };

  issueB(0);
  issueA(0);
  writeB(0);
  __syncthreads();

  int buf = 0;
  for (int s = 0; s < nks; ++s) {
    s16x8 ah[2], al[2];
    if (ASPLIT) {
      ah[0] = ahn[0]; ah[1] = ahn[1];
      al[0] = aln[0]; al[1] = aln[1];
    } else {
#pragma unroll
      for (int mb = 0; mb < 2; mb++) {
        float xv[8] = {araw[mb*2].x, araw[mb*2].y, araw[mb*2].z, araw[mb*2].w,
                       araw[mb*2+1].x, araw[mb*2+1].y, araw[mb*2+1].z, araw[mb*2+1].w};
        union { ushort u[8]; s16x8 v; } H, L;
#pragma unroll
        for (int e = 0; e < 8; e++) {
          ushort h = f2bf(xv[e]);
          H.u[e] = h;
          L.u[e] = f2bf(xv[e] - bf2f(h));
        }
        ah[mb] = H.v;
        al[mb] = L.v;
      }
    }
    const bool more = (s + 1 < nks);
    if (more) { issueB(s + 1); issueA(s + 1); }

#pragma unroll
    for (int nb = 0; nb < 8; nb++) {
      s16x8 bh = *(const s16x8*)&Bs[buf][nb * 512 + l * 8];
      s16x8 bl = *(const s16x8*)&Bs[buf][4096 + nb * 512 + l * 8];
#pragma unroll
      for (int mb = 0; mb < 2; mb++) {
        acc[mb][nb] = __builtin_amdgcn_mfma_f32_16x16x32_bf16(ah[mb], bh, acc[mb][nb], 0, 0, 0);
        acc[mb][nb] = __builtin_amdgcn_mfma_f32_16x16x32_bf16(ah[mb], bl, acc[mb][nb], 0, 0, 0);
        acc[mb][nb] = __builtin_amdgcn_mfma_f32_16x16x32_bf16(al[mb], bh, acc[mb][nb], 0, 0, 0);
      }
    }
    if (more) {
      writeB(buf ^ 1);
      __syncthreads();
      buf ^= 1;
    }
  }

  float dvr[2][4];
#pragma unroll
  for (int mb = 0; mb < 2; mb++)
#pragma unroll
    for (int r = 0; r < 4; r++)
      dvr[mb][r] = scale ? scale[r0 + mb * 16 + kg * 4 + r] : 1.f;

#pragma unroll
  for (int nb = 0; nb < 8; nb++) {
    int col = nb * 16 + lr;
    float bv = bias ? bias[col] : 0.f;
#pragma unroll
    for (int mb = 0; mb < 2; mb++)
#pragma unroll
      for (int r = 0; r < 4; r++) {
        size_t row = (size_t)(r0 + mb * 16 + kg * 4 + r);
        Y[row * FD + col] = f2bf((acc[mb][nb][r] + bv) * dvr[mb][r]);
      }
  }
}

// ---------------- GCN aggregation: bucket-wise LDS accumulate ------------------
// One 1024-thr block per bucket (256 nodes = 1 graph). 128 KB fp32 LDS
// accumulator. Wave-per-edge: all 64 lanes share one record (uniform), lane l
// covers dims {l, l+64} -> gathers are 2x 128B contiguous; LDS atomicAdd is
// row-uniform per wave -> 2 lanes/bank = conflict-free. 8 edges unrolled ->
// 16 gathers in flight per lane. No CSR, no padding, no divergence.
// out[n] = relu( dinv[n]*(sum_e t[src_e] + t[n]) + bias )
// EMIT=0: write hi/lo bf16 planes. EMIT=1: block-local segmax + fused MLP head.

template <int EMIT>
__global__ __launch_bounds__(1024) void k_agg(const ushort* __restrict__ h16,
                                              const uint* __restrict__ binbuf,
                                              const int* __restrict__ gbin,
                                              const float* __restrict__ dinv,
                                              const float* __restrict__ bias,
                                              ushort* __restrict__ yhi,
                                              ushort* __restrict__ ylo,
                                              const float* __restrict__ Wp1,
                                              const float* __restrict__ bp1,
                                              const float* __restrict__ Wp2,
                                              const float* __restrict__ bp2,
                                              float* __restrict__ out) {
  __shared__ float acc[256][128];  // 128 KB
  __shared__ float pm[8][128];
  __shared__ float red[128];
  const int b = blockIdx.x, t = threadIdx.x;

  for (int i = t; i < 256 * 128; i += 1024) ((float*)acc)[i] = 0.f;
  __syncthreads();

  const int m = gbin[b];
  const uint* bp_ = binbuf + (size_t)b * BCAP;
  const int wv = t >> 6;
  const int l = t & 63;

  int i = wv;
  for (; i + 112 < m; i += 128) {  // 16 waves x 8 edges per iter
    uint rr[8];
#pragma unroll
    for (int u = 0; u < 8; u++) rr[u] = bp_[i + u * 16];
    float va[8], vb[8];
#pragma unroll
    for (int u = 0; u < 8; u++) {
      const ushort* rowp = h16 + ((size_t)(rr[u] & 0xFFFFu) << 7) + l;
      va[u] = bf2f(rowp[0]);
      vb[u] = bf2f(rowp[64]);
    }
#pragma unroll
    for (int u = 0; u < 8; u++) {
      float* ap = &acc[rr[u] >> 16][l];
      atomicAdd(ap, va[u]);
      atomicAdd(ap + 64, vb[u]);
    }
  }
  for (; i < m; i += 16) {
    uint r = bp_[i];
    const ushort* rowp = h16 + ((size_t)(r & 0xFFFFu) << 7) + l;
    float* ap = &acc[r >> 16][l];
    atomicAdd(ap, bf2f(rowp[0]));
    atomicAdd(ap + 64, bf2f(rowp[64]));
  }
  __syncthreads();

  // epilogue: self term + bias + relu
  const int d = t & 127;
  const int j0 = t >> 7;  // 0..7
  float bb = bias[d];
  if (EMIT == 0) {
    for (int j = j0; j < 256; j += 8) {
      size_t n = (size_t)b * 256 + j;
      float o = fmaxf(fmaf(dinv[n], acc[j][d] + bf2f(h16[(n << 7) + d]), bb), 0.f);
      ushort hi = f2bf(o);
      yhi[(n << 7) + d] = hi;
      ylo[(n << 7) + d] = f2bf(o - bf2f(hi));
    }
  } else {
    float mx = 0.f;
    for (int j = j0; j < 256; j += 8) {
      size_t n = (size_t)b * 256 + j;
      float o = fmaxf(fmaf(dinv[n], acc[j][d] + bf2f(h16[(n << 7) + d]), bb), 0.f);
      mx = fmaxf(mx, o);
    }
    pm[j0][d] = mx;
    __syncthreads();
    if (t < 128) {
      float M = pm[0][t];
#pragma unroll
      for (int k = 1; k < 8; k++) M = fmaxf(M, pm[k][t]);
      pm[0][t] = M;  // pooled row for this graph
    }
    __syncthreads();
    // fused MLP head: out[b] = relu(pooled@Wp1+bp1)@Wp2 + bp2
    if (t < 128) {
      float a = bp1[t];
#pragma unroll 8
      for (int k = 0; k < 128; k++) a = fmaf(pm[0][k], Wp1[k * FD + t], a);
      red[t] = fmaxf(a, 0.f) * Wp2[t];
    }
    __syncthreads();
    for (int st = 64; st > 0; st >>= 1) {
      if (t < st) red[t] += red[t + st];
      __syncthreads();
    }
    if (t == 0) out[b] = red[0] + bp2[0];
  }
}

// ---------------- launch ----------------

extern "C" void kernel_launch(void* const* d_in, const int* in_sizes, int n_in,
                              void* d_out, int out_size, void* d_ws, size_t ws_size,
                              hipStream_t stream) {
  (void)in_sizes; (void)n_in; (void)out_size; (void)ws_size;

  const float* adj  = (const float*)d_in[0];
  const int*   edges= (const int*)d_in[1];
  const float* Wdec = (const float*)d_in[3];
  const float* bdec = (const float*)d_in[4];
  const float* Wc1  = (const float*)d_in[5];
  const float* bc1  = (const float*)d_in[6];
  const float* Wc2  = (const float*)d_in[7];
  const float* bc2  = (const float*)d_in[8];
  const float* Wp1  = (const float*)d_in[9];
  const float* bp1  = (const float*)d_in[10];
  const float* Wp2  = (const float*)d_in[11];
  const float* bp2  = (const float*)d_in[12];
  float* out = (float*)d_out;

  char* ws = (char*)d_ws;
  size_t off = 0;
  auto alloc = [&](size_t bytes) -> void* {
    void* p = ws + off;
    off += (bytes + 255) & ~(size_t)255;
    return p;
  };
  ushort* h16  = (ushort*)alloc((size_t)NN * FD * 2);  // 16 MB table (t = dinv*h)
  ushort* x1hi = (ushort*)alloc((size_t)NN * FD * 2);
  ushort* x1lo = (ushort*)alloc((size_t)NN * FD * 2);
  int*    gbin = (int*)alloc(256 * 4);
  uint*   binbuf = (uint*)alloc((size_t)256 * BCAP * 4);  // 4.7 MB bucket bins
  float*  dinv = (float*)alloc((size_t)NN * 4);
  float*  bfused = (float*)alloc(FD * 4);
  ushort* wfh = (ushort*)alloc((size_t)KDEC * FD * 2);
  ushort* wfl = (ushort*)alloc((size_t)KDEC * FD * 2);
  ushort* w2h = (ushort*)alloc((size_t)FD * FD * 2);
  ushort* w2l = (ushort*)alloc((size_t)FD * FD * 2);

  hipMemsetAsync(gbin, 0, 256 * 4, stream);

  // bin edges into per-bucket chunks (only CSR-ish structure needed)
  k_histbin<<<256, 1024, 0, stream>>>(edges, binbuf, gbin);
  // dinv (bucket-local count) | Wfused=Wdec@Wc1 -> split planes (+bfused) | Wc2 prep
  k_misc1<<<448, 256, 0, stream>>>(binbuf, gbin, dinv, Wdec, Wc1, bdec,
                                   bfused, wfh, wfl, Wc2, w2h, w2l);

  // t1 = dinv * (adj @ Wfused + bfused) -> bf16 table
  k_gemm<false><<<NN / 128, 256, 0, stream>>>(adj, nullptr, wfh, wfl, bfused, dinv, h16, KDEC);

  // x1 = relu(dinv*(sum t1 + t1_self) + bc1) -> hi/lo planes (bucket-wise LDS agg)
  k_agg<0><<<256, 1024, 0, stream>>>(h16, binbuf, gbin, dinv, bc1, x1hi, x1lo,
                                     nullptr, nullptr, nullptr, nullptr, nullptr);

  // t2 = dinv * (x1 @ Wc2) -> bf16 table
  k_gemm<true><<<NN / 128, 256, 0, stream>>>(x1hi, x1lo, w2h, w2l, nullptr, dinv, h16, FD);

  // layer 2 agg + segmax + MLP head, all block-local (bucket == graph)
  k_agg<1><<<256, 1024, 0, stream>>>(h16, binbuf, gbin, dinv, bc2, nullptr, nullptr,
                                     Wp1, bp1, Wp2, bp2, out);
}

// Round 14
// 166.512 us; speedup vs baseline: 8.7616x; 8.7616x over previous
//
#include <hip/hip_runtime.h>
#include <hip/hip_fp16.h>
#include <cstdint>
#include <cstddef>

// Problem constants: B=256, C=1, NMAX=256 -> N=65536 nodes, E=N*16=1048576,
// EMB=HID=128, decode K = NMAX = 256. Bucket b (= dst>>8) == graph b.
#define NN   65536
#define NE   1048576
#define FD   128
#define KDEC 256
#define NGRAPH 256
// padded edge capacity: sum ceil(cnt/16)*16 <= NE + 15*NN
#define NEP_MAX (NE + 15 * NN)   // 2031616 records
#define DUMMY_SRC 65536u         // zero row index
#define EPB  4096                // edges per binning block
#define BCAP 4608                // per-bucket record capacity (mean 4096 + 8 sigma)

typedef __attribute__((ext_vector_type(8))) short s16x8;
typedef __attribute__((ext_vector_type(4))) float f32x4;

__device__ __forceinline__ ushort f2bf(float x) {
  uint u = __float_as_uint(x);
  uint r = (u + 0x7fffu + ((u >> 16) & 1u)) >> 16;  // RNE
  return (ushort)r;
}
__device__ __forceinline__ float bf2f(ushort h) {
  return __uint_as_float(((uint)h) << 16);
}

// ---------------- edge binning: radix-partition into per-bucket chunks --------
// 256 blocks (1024 thr): 4096 edges each. LDS count -> scan -> LDS-sorted
// placement -> coalesced streamed write into each bucket's binbuf chunk.

__global__ __launch_bounds__(1024) void k_histbin(const int* __restrict__ edges,
                                                  uint* __restrict__ binbuf,
                                                  int* __restrict__ gbin) {
  const int b = blockIdx.x, t = threadIdx.x;
  __shared__ int lcnt[256];
  __shared__ int lsum[256];   // inclusive prefix of lcnt
  __shared__ int gbase[256];
  __shared__ uint sorted[EPB];

  if (t < 256) lcnt[t] = 0;
  __syncthreads();

  uint rec[4];
  ushort bkt[4], lidx[4];
#pragma unroll
  for (int r = 0; r < 4; r++) {
    int i = b * EPB + r * 1024 + t;
    int2 e = ((const int2*)edges)[i];
    int bucket = e.y >> 8;
    int li = atomicAdd(&lcnt[bucket], 1);
    rec[r] = ((uint)bucket << 24) | ((uint)(e.y & 255) << 16) | (uint)e.x;
    bkt[r] = (ushort)bucket;
    lidx[r] = (ushort)li;
  }
  __syncthreads();

  if (t < 256) lsum[t] = lcnt[t];
  __syncthreads();
  for (int off = 1; off < 256; off <<= 1) {
    int v = 0;
    if (t < 256 && t >= off) v = lsum[t - off];
    __syncthreads();
    if (t < 256) lsum[t] += v;
    __syncthreads();
  }
  if (t < 256) gbase[t] = atomicAdd(&gbin[t], lcnt[t]);
  __syncthreads();

#pragma unroll
  for (int r = 0; r < 4; r++) {
    int B = bkt[r];
    sorted[lsum[B] - lcnt[B] + lidx[r]] = rec[r];
  }
  __syncthreads();

  for (int s = t; s < EPB; s += 1024) {
    uint v = sorted[s];
    int B = v >> 24;
    int ex = lsum[B] - lcnt[B];
    binbuf[B * BCAP + gbase[B] + (s - ex)] = v & 0xFFFFFFu;  // (dlow<<16)|src
  }
}

// misc1: blocks 0-255: bucket-local node histogram (LDS counters) -> hist +
//        padded bsum[b]. 256-383: Wfused=Wdec@Wc1 fp32 (+bfused). 384-447: prep Wc2.
// frag dst(k,c) = ((k/32)*8 + c/16)*512 + ((c&15) + 16*((k&31)>>3))*8 + (k&7)
__device__ __forceinline__ void prep_one(const float* __restrict__ W,
                                         ushort* __restrict__ H,
                                         ushort* __restrict__ L, int i) {
  int k = i >> 7, c = i & 127;
  float w = W[i];
  ushort h = f2bf(w);
  ushort lo = f2bf(w - bf2f(h));
  size_t dst = ((size_t)((k >> 5) * 8 + (c >> 4)) * 64 +
                (size_t)((c & 15) + 16 * ((k & 31) >> 3))) * 8 + (k & 7);
  H[dst] = h;
  L[dst] = lo;
}

__global__ __launch_bounds__(256) void k_misc1(const uint* __restrict__ binbuf,
                                               const int* __restrict__ gbin,
                                               int* __restrict__ hist,
                                               int* __restrict__ bsum,
                                               const float* __restrict__ Wdec,
                                               const float* __restrict__ Wc1,
                                               const float* __restrict__ bdec,
                                               float* __restrict__ wfused,
                                               float* __restrict__ bfused,
                                               const float* __restrict__ Wc2,
                                               ushort* __restrict__ w2h,
                                               ushort* __restrict__ w2l) {
  int b = blockIdx.x, t = threadIdx.x;
  if (b < 256) {
    __shared__ int lc[256];
    __shared__ int s[256];
    lc[t] = 0;
    __syncthreads();
    int m = gbin[b];
    for (int i = t; i < m; i += 256)
      atomicAdd(&lc[binbuf[b * BCAP + i] >> 16], 1);
    __syncthreads();
    hist[b * 256 + t] = lc[t];
    s[t] = (lc[t] + 15) & ~15;  // padded
    __syncthreads();
    for (int st = 128; st > 0; st >>= 1) {
      if (t < st) s[t] += s[t + st];
      __syncthreads();
    }
    if (t == 0) bsum[b] = s[0];
  } else if (b < 384) {
    int i = (b - 256) * 256 + t;  // 0..32767
    int k = i >> 7, c = i & 127;
    float acc = 0.f;
#pragma unroll 8
    for (int j = 0; j < 128; j++) acc = fmaf(Wdec[k * FD + j], Wc1[j * FD + c], acc);
    wfused[i] = acc;
    if (b == 256 && t < 128) {
      float ba = 0.f;
      for (int j = 0; j < 128; j++) ba = fmaf(bdec[j], Wc1[j * FD + t], ba);
      bfused[t] = ba;
    }
  } else {
    int i = (b - 384) * 256 + t;  // 0..16383
    prep_one(Wc2, w2h, w2l, i);
  }
}

// misc2: blocks 0-255: scanfinal over PADDED counts (scanb fused) + dinv, THEN
//        the bucket's CSR scatter in-block (offsets from LDS, L2-local window)
//        including targeted padding-slot fill (replaces the 8MB blanket prefill).
//        blocks 256-383: prep Wfused.
__global__ __launch_bounds__(256) void k_misc2(const int* __restrict__ hist,
                                               const int* __restrict__ bsum,
                                               int* __restrict__ offs,
                                               float* __restrict__ dinv,
                                               const float* __restrict__ wfused,
                                               ushort* __restrict__ wfh,
                                               ushort* __restrict__ wfl,
                                               const uint* __restrict__ binbuf,
                                               const int* __restrict__ gbin,
                                               uint* __restrict__ ec) {
  int b = blockIdx.x, t = threadIdx.x;
  if (b < 256) {
    __shared__ int sb[256];
    __shared__ int s[256];
    __shared__ int sofs[256];
    __shared__ int cnt2[256];
    sb[t] = bsum[t];
    int v = hist[b * 256 + t];
    int vp = (v + 15) & ~15;
    s[t] = vp;
    __syncthreads();
    for (int off = 1; off < 256; off <<= 1) {
      int addb = (t >= off) ? sb[t - off] : 0;
      int add = (t >= off) ? s[t - off] : 0;
      __syncthreads();
      sb[t] += addb;
      s[t] += add;
      __syncthreads();
    }
    int pb = (b > 0) ? sb[b - 1] : 0;
    int of = pb + s[t] - vp;  // padded exclusive offset for node b*256+t
    offs[b * 256 + t] = of;
    sofs[t] = of;
    dinv[b * 256 + t] = rsqrtf((float)(v + 1));
    cnt2[t] = 0;
    __syncthreads();

    // bucket scatter: sequential reads, writes confined to this bucket's window
    int m = gbin[b];
    for (int i = t; i < m; i += 256) {
      uint rec = binbuf[(size_t)b * BCAP + i];
      int dlow = rec >> 16;
      int pos = sofs[dlow] + atomicAdd(&cnt2[dlow], 1);
      ec[pos] = rec & 0xFFFFu;
    }
    __syncthreads();
    // targeted padding fill: node t's slots [v, vp)
    int base = sofs[t];
    for (int j = v; j < vp; j++) ec[base + j] = DUMMY_SRC;
  } else {
    int i = (b - 256) * 256 + t;  // 0..32767
    prep_one(wfused, wfh, wfl, i);
  }
}

// ---------------- split-bf16 MFMA GEMM, LDS-B double-buffered pipeline ----------
// (round-12 proven) 256 thr = 4 waves; wave owns 32 rows; BM=128. B staged once
// per block per K-step into double-buffered LDS; A prefetched one K-step ahead.

template <bool ASPLIT>
__global__ __launch_bounds__(256) void k_gemm(const void* __restrict__ A0,
                                              const void* __restrict__ A1,
                                              const ushort* __restrict__ Whi,
                                              const ushort* __restrict__ Wlo,
                                              const float* __restrict__ bias,
                                              const float* __restrict__ scale,
                                              ushort* __restrict__ Y, int K) {
  __shared__ ushort Bs[2][8192];  // [buf][hi 4096 | lo 4096] = 32 KB
  const int t = threadIdx.x;
  const int w = t >> 6;
  const int l = t & 63;
  const int lr = l & 15;
  const int kg = l >> 4;
  const int r0 = blockIdx.x * 128 + w * 32;
  const int nks = K >> 5;

  f32x4 acc[2][8];
#pragma unroll
  for (int mb = 0; mb < 2; mb++)
#pragma unroll
    for (int nb = 0; nb < 8; nb++) acc[mb][nb] = (f32x4)0.f;

  f32x4 araw[4];
  s16x8 ahn[2], aln[2];
  s16x8 bh0, bh1, bl0, bl1;

  auto issueA = [&](int s) {
#pragma unroll
    for (int mb = 0; mb < 2; mb++) {
      size_t base = (size_t)(r0 + mb * 16 + lr) * K + s * 32 + kg * 8;
      if (ASPLIT) {
        ahn[mb] = *(const s16x8*)((const ushort*)A0 + base);
        aln[mb] = *(const s16x8*)((const ushort*)A1 + base);
      } else {
        const float* xp = (const float*)A0 + base;
        araw[mb * 2] = *(const f32x4*)xp;
        araw[mb * 2 + 1] = *(const f32x4*)(xp + 4);
      }
    }
  };
  auto issueB = [&](int s) {
    const ushort* ph = Whi + (size_t)s * 4096 + t * 16;
    const ushort* pl = Wlo + (size_t)s * 4096 + t * 16;
    bh0 = *(const s16x8*)ph;
    bh1 = *(const s16x8*)(ph + 8);
    bl0 = *(const s16x8*)pl;
    bl1 = *(const s16x8*)(pl + 8);
  };
  auto writeB = [&](int buf) {
    *(s16x8*)&Bs[buf][t * 16] = bh0;
    *(s16x8*)&Bs[buf][t * 16 + 8] = bh1;
    *(s16x8*)&Bs[buf][4096 + t * 16] = bl0;
    *(s16x8*)&Bs[buf][4096 + t * 16 + 8] = bl1;
  };

  issueB(0);
  issueA(0);
  writeB(0);
  __syncthreads();

  int buf = 0;
  for (int s = 0; s < nks; ++s) {
    s16x8 ah[2], al[2];
    if (ASPLIT) {
      ah[0] = ahn[0]; ah[1] = ahn[1];
      al[0] = aln[0]; al[1] = aln[1];
    } else {
#pragma unroll
      for (int mb = 0; mb < 2; mb++) {
        float xv[8] = {araw[mb*2].x, araw[mb*2].y, araw[mb*2].z, araw[mb*2].w,
                       araw[mb*2+1].x, araw[mb*2+1].y, araw[mb*2+1].z, araw[mb*2+1].w};
        union { ushort u[8]; s16x8 v; } H, L;
#pragma unroll
        for (int e = 0; e < 8; e++) {
          ushort h = f2bf(xv[e]);
          H.u[e] = h;
          L.u[e] = f2bf(xv[e] - bf2f(h));
        }
        ah[mb] = H.v;
        al[mb] = L.v;
      }
    }
    const bool more = (s + 1 < nks);
    if (more) { issueB(s + 1); issueA(s + 1); }

#pragma unroll
    for (int nb = 0; nb < 8; nb++) {
      s16x8 bh = *(const s16x8*)&Bs[buf][nb * 512 + l * 8];
      s16x8 bl = *(const s16x8*)&Bs[buf][4096 + nb * 512 + l * 8];
#pragma unroll
      for (int mb = 0; mb < 2; mb++) {
        acc[mb][nb] = __builtin_amdgcn_mfma_f32_16x16x32_bf16(ah[mb], bh, acc[mb][nb], 0, 0, 0);
        acc[mb][nb] = __builtin_amdgcn_mfma_f32_16x16x32_bf16(ah[mb], bl, acc[mb][nb], 0, 0, 0);
        acc[mb][nb] = __builtin_amdgcn_mfma_f32_16x16x32_bf16(al[mb], bh, acc[mb][nb], 0, 0, 0);
      }
    }
    if (more) {
      writeB(buf ^ 1);
      __syncthreads();
      buf ^= 1;
    }
  }

  float dvr[2][4];
#pragma unroll
  for (int mb = 0; mb < 2; mb++)
#pragma unroll
    for (int r = 0; r < 4; r++)
      dvr[mb][r] = scale ? scale[r0 + mb * 16 + kg * 4 + r] : 1.f;

#pragma unroll
  for (int nb = 0; nb < 8; nb++) {
    int col = nb * 16 + lr;
    float bv = bias ? bias[col] : 0.f;
#pragma unroll
    for (int mb = 0; mb < 2; mb++)
#pragma unroll
      for (int r = 0; r < 4; r++) {
        size_t row = (size_t)(r0 + mb * 16 + kg * 4 + r);
        Y[row * FD + col] = f2bf((acc[mb][nb][r] + bv) * dvr[mb][r]);
      }
  }
}

// ---------------- GCN aggregation: wave-per-node, UNIFORM 8-deep pipeline ------
// (round-11/12 proven) Table t = dinv*h, bf16 [NN+1][128] (row NN = zeros).
// out[d] = relu( dinv[d]*(sum_e t[src_e] + t[d]) + b )
// EMIT=0: write hi/lo bf16 planes. EMIT=1: fused segment-max pooling.

template <int EMIT>
__global__ __launch_bounds__(256) void k_agg(const ushort* __restrict__ h16,
                                             const uint* __restrict__ ec,
                                             const int* __restrict__ offs,
                                             const int* __restrict__ hist,
                                             const float* __restrict__ dinv,
                                             const float* __restrict__ bias,
                                             ushort* __restrict__ yhi,
                                             ushort* __restrict__ ylo,
                                             float* __restrict__ pooled) {
  __shared__ int pmax[128];
  const int t = threadIdx.x;
  if (EMIT == 1) {
    if (t < 128) pmax[t] = 0;
    __syncthreads();
  }
  const int n = blockIdx.x * 4 + (t >> 6);
  const int l = t & 63;
  const int half = l >> 5;
  const int dl = (l & 31) * 4;

  const int cnt_p = (hist[n] + 15) & ~15;  // padded count
  const uint* ep = ec + offs[n];

  float a0 = 0.f, a1 = 0.f, a2 = 0.f, a3 = 0.f;
  float b0 = 0.f, b1 = 0.f, b2 = 0.f, b3 = 0.f;
  for (int i = half; i < cnt_p; i += 16) {
    uint s0 = ep[i];
    uint s1 = ep[i + 2];
    uint s2 = ep[i + 4];
    uint s3 = ep[i + 6];
    uint s4 = ep[i + 8];
    uint s5 = ep[i + 10];
    uint s6 = ep[i + 12];
    uint s7 = ep[i + 14];
    ushort4 v0 = *(const ushort4*)(h16 + ((size_t)s0 << 7) + dl);
    ushort4 v1 = *(const ushort4*)(h16 + ((size_t)s1 << 7) + dl);
    ushort4 v2 = *(const ushort4*)(h16 + ((size_t)s2 << 7) + dl);
    ushort4 v3 = *(const ushort4*)(h16 + ((size_t)s3 << 7) + dl);
    ushort4 v4 = *(const ushort4*)(h16 + ((size_t)s4 << 7) + dl);
    ushort4 v5 = *(const ushort4*)(h16 + ((size_t)s5 << 7) + dl);
    ushort4 v6 = *(const ushort4*)(h16 + ((size_t)s6 << 7) + dl);
    ushort4 v7 = *(const ushort4*)(h16 + ((size_t)s7 << 7) + dl);
    a0 += bf2f(v0.x); a1 += bf2f(v0.y); a2 += bf2f(v0.z); a3 += bf2f(v0.w);
    b0 += bf2f(v1.x); b1 += bf2f(v1.y); b2 += bf2f(v1.z); b3 += bf2f(v1.w);
    a0 += bf2f(v2.x); a1 += bf2f(v2.y); a2 += bf2f(v2.z); a3 += bf2f(v2.w);
    b0 += bf2f(v3.x); b1 += bf2f(v3.y); b2 += bf2f(v3.z); b3 += bf2f(v3.w);
    a0 += bf2f(v4.x); a1 += bf2f(v4.y); a2 += bf2f(v4.z); a3 += bf2f(v4.w);
    b0 += bf2f(v5.x); b1 += bf2f(v5.y); b2 += bf2f(v5.z); b3 += bf2f(v5.w);
    a0 += bf2f(v6.x); a1 += bf2f(v6.y); a2 += bf2f(v6.z); a3 += bf2f(v6.w);
    b0 += bf2f(v7.x); b1 += bf2f(v7.y); b2 += bf2f(v7.z); b3 += bf2f(v7.w);
  }
  a0 += b0; a1 += b1; a2 += b2; a3 += b3;
  a0 += __shfl_xor(a0, 32);
  a1 += __shfl_xor(a1, 32);
  a2 += __shfl_xor(a2, 32);
  a3 += __shfl_xor(a3, 32);

  if (l < 32) {
    float dv = dinv[n];
    ushort4 vs = *(const ushort4*)(h16 + ((size_t)n << 7) + dl);  // t[d]
    float4 bb = *(const float4*)(bias + dl);
    float o0 = fmaxf(fmaf(dv, a0 + bf2f(vs.x), bb.x), 0.f);
    float o1 = fmaxf(fmaf(dv, a1 + bf2f(vs.y), bb.y), 0.f);
    float o2 = fmaxf(fmaf(dv, a2 + bf2f(vs.z), bb.z), 0.f);
    float o3 = fmaxf(fmaf(dv, a3 + bf2f(vs.w), bb.w), 0.f);
    if (EMIT == 0) {
      ushort4 hi, lo;
      hi.x = f2bf(o0); lo.x = f2bf(o0 - bf2f(hi.x));
      hi.y = f2bf(o1); lo.y = f2bf(o1 - bf2f(hi.y));
      hi.z = f2bf(o2); lo.z = f2bf(o2 - bf2f(hi.z));
      hi.w = f2bf(o3); lo.w = f2bf(o3 - bf2f(hi.w));
      size_t base = (size_t)n * FD + dl;
      *(ushort4*)(yhi + base) = hi;
      *(ushort4*)(ylo + base) = lo;
    } else {
      // relu>=0: int-compare == float-compare for non-negative floats
      atomicMax(&pmax[dl + 0], __float_as_int(o0));
      atomicMax(&pmax[dl + 1], __float_as_int(o1));
      atomicMax(&pmax[dl + 2], __float_as_int(o2));
      atomicMax(&pmax[dl + 3], __float_as_int(o3));
    }
  }
  if (EMIT == 1) {
    __syncthreads();
    if (t < 128) {
      int gr = blockIdx.x >> 6;  // 64 blocks (256 nodes) per graph
      atomicMax((int*)pooled + gr * FD + t, pmax[t]);
    }
  }
}

// ---------------- MLP head ----------------

__global__ __launch_bounds__(128) void k_mlp(const float* __restrict__ pooled,
                                             const float* __restrict__ Wp1,
                                             const float* __restrict__ bp1,
                                             const float* __restrict__ Wp2,
                                             const float* __restrict__ bp2,
                                             float* __restrict__ out) {
  __shared__ float row[128];
  __shared__ float red[128];
  int g = blockIdx.x, t = threadIdx.x;
  row[t] = pooled[g * FD + t];
  __syncthreads();
  float acc = bp1[t];
#pragma unroll 8
  for (int k = 0; k < 128; k++) acc = fmaf(row[k], Wp1[k * FD + t], acc);
  acc = fmaxf(acc, 0.f);
  red[t] = acc * Wp2[t];
  __syncthreads();
  for (int st = 64; st > 0; st >>= 1) {
    if (t < st) red[t] += red[t + st];
    __syncthreads();
  }
  if (t == 0) out[g] = red[0] + bp2[0];
}

// ---------------- launch ----------------

extern "C" void kernel_launch(void* const* d_in, const int* in_sizes, int n_in,
                              void* d_out, int out_size, void* d_ws, size_t ws_size,
                              hipStream_t stream) {
  (void)in_sizes; (void)n_in; (void)out_size; (void)ws_size;

  const float* adj  = (const float*)d_in[0];
  const int*   edges= (const int*)d_in[1];
  const float* Wdec = (const float*)d_in[3];
  const float* bdec = (const float*)d_in[4];
  const float* Wc1  = (const float*)d_in[5];
  const float* bc1  = (const float*)d_in[6];
  const float* Wc2  = (const float*)d_in[7];
  const float* bc2  = (const float*)d_in[8];
  const float* Wp1  = (const float*)d_in[9];
  const float* bp1  = (const float*)d_in[10];
  const float* Wp2  = (const float*)d_in[11];
  const float* bp2  = (const float*)d_in[12];
  float* out = (float*)d_out;

  char* ws = (char*)d_ws;
  size_t off = 0;
  auto alloc = [&](size_t bytes) -> void* {
    void* p = ws + off;
    off += (bytes + 255) & ~(size_t)255;
    return p;
  };
  ushort* h16  = (ushort*)alloc((size_t)(NN + 1) * FD * 2);  // +1 zero row
  ushort* x1hi = (ushort*)alloc((size_t)NN * FD * 2);
  ushort* x1lo = (ushort*)alloc((size_t)NN * FD * 2);
  // pooled | gbin contiguous -> single memset
  float*  pooled = (float*)alloc((size_t)NGRAPH * FD * 4);
  int*    gbin = (int*)alloc(256 * 4);
  int*    hist = (int*)alloc((size_t)NN * 4);
  int*    offs = (int*)alloc((size_t)NN * 4);
  int*    bsum = (int*)alloc(256 * 4);
  uint*   ec   = (uint*)alloc((size_t)NEP_MAX * 4);    // 8.1 MB padded records
  uint*   binbuf = (uint*)alloc((size_t)256 * BCAP * 4);  // 4.7 MB bucket bins
  float*  dinv = (float*)alloc((size_t)NN * 4);
  float*  wfused = (float*)alloc((size_t)KDEC * FD * 4);
  float*  bfused = (float*)alloc(FD * 4);
  ushort* wfh = (ushort*)alloc((size_t)KDEC * FD * 2);
  ushort* wfl = (ushort*)alloc((size_t)KDEC * FD * 2);
  ushort* w2h = (ushort*)alloc((size_t)FD * FD * 2);
  ushort* w2l = (ushort*)alloc((size_t)FD * FD * 2);

  hipMemsetAsync(pooled, 0, (size_t)NGRAPH * FD * 4 + 256 * 4, stream);
  hipMemsetAsync(h16 + (size_t)NN * FD, 0, FD * 2, stream);  // zero row (dummy target)

  // radix-partition binning (pure; no hist atomics, no ec prefill)
  k_histbin<<<256, 1024, 0, stream>>>(edges, binbuf, gbin);
  // bucket-hist (LDS-local) -> hist + padded bsum | Wfused (+bfused) | prep Wc2
  k_misc1<<<448, 256, 0, stream>>>(binbuf, gbin, hist, bsum, Wdec, Wc1, bdec,
                                   wfused, bfused, Wc2, w2h, w2l);
  // scanfinal + dinv + bucket scatter (incl. targeted padding fill) | prep Wfused
  k_misc2<<<384, 256, 0, stream>>>(hist, bsum, offs, dinv, wfused, wfh, wfl,
                                   binbuf, gbin, ec);

  // t1 = dinv * (adj @ Wfused + bfused) -> bf16 table
  k_gemm<false><<<NN / 128, 256, 0, stream>>>(adj, nullptr, wfh, wfl, bfused, dinv, h16, KDEC);

  // x1 = relu(dinv*(sum t1 + t1_self) + bc1) -> hi/lo planes
  k_agg<0><<<NN / 4, 256, 0, stream>>>(h16, ec, offs, hist, dinv, bc1, x1hi, x1lo, nullptr);

  // t2 = dinv * (x1 @ Wc2) -> bf16 table
  k_gemm<true><<<NN / 128, 256, 0, stream>>>(x1hi, x1lo, w2h, w2l, nullptr, dinv, h16, FD);

  // pooled = segmax(relu(dinv*(sum t2 + t2_self) + bc2)) fused
  k_agg<1><<<NN / 4, 256, 0, stream>>>(h16, ec, offs, hist, dinv, bc2, nullptr, nullptr, pooled);

  // MLP head
  k_mlp<<<NGRAPH, 128, 0, stream>>>(pooled, Wp1, bp1, Wp2, bp2, out);
}

// Round 15
// 166.171 us; speedup vs baseline: 8.7796x; 1.0021x over previous
//
#include <hip/hip_runtime.h>
#include <hip/hip_fp16.h>
#include <cstdint>
#include <cstddef>

// Problem constants: B=256, C=1, NMAX=256 -> N=65536 nodes, E=N*16=1048576,
// EMB=HID=128, decode K = NMAX = 256. Bucket b (= dst>>8) == graph b.
#define NN   65536
#define NE   1048576
#define FD   128
#define KDEC 256
#define NGRAPH 256
#define DUMMY_SRC 65536u         // zero row index
#define EPB  4096                // edges per binning block
#define BCAP 4608                // per-bucket record capacity (mean 4096 + 8 sigma)
#define BCAPP 8448               // per-bucket PADDED ec window (BCAP + 15*256)

typedef __attribute__((ext_vector_type(8))) short s16x8;
typedef __attribute__((ext_vector_type(4))) float f32x4;

__device__ __forceinline__ ushort f2bf(float x) {
  uint u = __float_as_uint(x);
  uint r = (u + 0x7fffu + ((u >> 16) & 1u)) >> 16;  // RNE
  return (ushort)r;
}
__device__ __forceinline__ float bf2f(ushort h) {
  return __uint_as_float(((uint)h) << 16);
}

// W split helper (fragment-major):
// dst(k,c) = ((k/32)*8 + c/16)*512 + ((c&15) + 16*((k&31)>>3))*8 + (k&7)
__device__ __forceinline__ void wsplit(float w, int k, int c,
                                       ushort* __restrict__ H,
                                       ushort* __restrict__ L) {
  ushort h = f2bf(w);
  size_t dst = ((size_t)((k >> 5) * 8 + (c >> 4)) * 64 +
                (size_t)((c & 15) + 16 * ((k & 31) >> 3))) * 8 + (k & 7);
  H[dst] = h;
  L[dst] = f2bf(w - bf2f(h));
}

// ---------------- histbin: edge binning + ALL weight prep (parallel roles) ----
// blocks 0..255 (1024 thr): 4096 edges each -> LDS count/scan/sort -> coalesced
//   streamed write into per-bucket binbuf chunks.
// blocks 256..287: Wfused = Wdec@Wc1, computed and split DIRECTLY to planes
//   (+bfused in block 256). blocks 288..303: Wc2 -> split planes.

__global__ __launch_bounds__(1024) void k_histbin(const int* __restrict__ edges,
                                                  uint* __restrict__ binbuf,
                                                  int* __restrict__ gbin,
                                                  const float* __restrict__ Wdec,
                                                  const float* __restrict__ Wc1,
                                                  const float* __restrict__ bdec,
                                                  float* __restrict__ bfused,
                                                  ushort* __restrict__ wfh,
                                                  ushort* __restrict__ wfl,
                                                  const float* __restrict__ Wc2,
                                                  ushort* __restrict__ w2h,
                                                  ushort* __restrict__ w2l) {
  const int b = blockIdx.x, t = threadIdx.x;
  if (b >= 256) {
    if (b < 288) {
      int i = (b - 256) * 1024 + t;  // 0..32767
      int k = i >> 7, c = i & 127;
      float acc = 0.f;
#pragma unroll 8
      for (int j = 0; j < 128; j++) acc = fmaf(Wdec[k * FD + j], Wc1[j * FD + c], acc);
      wsplit(acc, k, c, wfh, wfl);
      if (b == 256 && t < 128) {
        float ba = 0.f;
        for (int j = 0; j < 128; j++) ba = fmaf(bdec[j], Wc1[j * FD + t], ba);
        bfused[t] = ba;
      }
    } else {
      int i = (b - 288) * 1024 + t;  // 0..16383
      wsplit(Wc2[i], i >> 7, i & 127, w2h, w2l);
    }
    return;
  }
  __shared__ int lcnt[256];
  __shared__ int lsum[256];   // inclusive prefix of lcnt
  __shared__ int gbase[256];
  __shared__ uint sorted[EPB];

  if (t < 256) lcnt[t] = 0;
  __syncthreads();

  uint rec[4];
  ushort bkt[4], lidx[4];
#pragma unroll
  for (int r = 0; r < 4; r++) {
    int i = b * EPB + r * 1024 + t;
    int2 e = ((const int2*)edges)[i];
    int bucket = e.y >> 8;
    int li = atomicAdd(&lcnt[bucket], 1);
    rec[r] = ((uint)bucket << 24) | ((uint)(e.y & 255) << 16) | (uint)e.x;
    bkt[r] = (ushort)bucket;
    lidx[r] = (ushort)li;
  }
  __syncthreads();

  if (t < 256) lsum[t] = lcnt[t];
  __syncthreads();
  for (int off = 1; off < 256; off <<= 1) {
    int v = 0;
    if (t < 256 && t >= off) v = lsum[t - off];
    __syncthreads();
    if (t < 256) lsum[t] += v;
    __syncthreads();
  }
  if (t < 256) gbase[t] = atomicAdd(&gbin[t], lcnt[t]);
  __syncthreads();

#pragma unroll
  for (int r = 0; r < 4; r++) {
    int B = bkt[r];
    sorted[lsum[B] - lcnt[B] + lidx[r]] = rec[r];
  }
  __syncthreads();

  for (int s = t; s < EPB; s += 1024) {
    uint v = sorted[s];
    int B = v >> 24;
    int ex = lsum[B] - lcnt[B];
    binbuf[B * BCAP + gbase[B] + (s - ex)] = v & 0xFFFFFFu;  // (dlow<<16)|src
  }
}

// ---------------- misc: bucket-local CSR build, one pass, no global scan -------
// Block b owns bucket b and its FIXED ec window [b*BCAPP, (b+1)*BCAPP):
// count (LDS) -> local padded scan -> offs/hist/dinv -> scatter -> pad fill.
// All block-local; no cross-block dependencies.

__global__ __launch_bounds__(256) void k_misc(const uint* __restrict__ binbuf,
                                              const int* __restrict__ gbin,
                                              int* __restrict__ hist,
                                              int* __restrict__ offs,
                                              float* __restrict__ dinv,
                                              uint* __restrict__ ec) {
  __shared__ int lc[256];
  __shared__ int s[256];
  __shared__ int sofs[256];
  __shared__ int cnt2[256];
  const int b = blockIdx.x, t = threadIdx.x;
  lc[t] = 0;
  cnt2[t] = 0;
  __syncthreads();
  const int m = gbin[b];
  const uint* bp_ = binbuf + (size_t)b * BCAP;
  for (int i = t; i < m; i += 256)
    atomicAdd(&lc[bp_[i] >> 16], 1);
  __syncthreads();
  const int v = lc[t];
  const int vp = (v + 15) & ~15;
  s[t] = vp;
  __syncthreads();
  for (int off = 1; off < 256; off <<= 1) {
    int add = (t >= off) ? s[t - off] : 0;
    __syncthreads();
    s[t] += add;
    __syncthreads();
  }
  const int of = b * BCAPP + s[t] - vp;  // absolute padded exclusive offset
  offs[b * 256 + t] = of;
  hist[b * 256 + t] = v;
  dinv[b * 256 + t] = rsqrtf((float)(v + 1));
  sofs[t] = of;
  __syncthreads();

  // scatter into this bucket's L2-local window
  for (int i = t; i < m; i += 256) {
    uint rec = bp_[i];
    int dlow = rec >> 16;
    int pos = sofs[dlow] + atomicAdd(&cnt2[dlow], 1);
    ec[pos] = rec & 0xFFFFu;
  }
  __syncthreads();
  // targeted padding fill: node t's slots [v, vp)
  int base = sofs[t];
  for (int j = v; j < vp; j++) ec[base + j] = DUMMY_SRC;
}

// ---------------- split-bf16 MFMA GEMM, LDS-B double-buffered pipeline ----------
// (round-12 proven) 256 thr = 4 waves; wave owns 32 rows; BM=128. B staged once
// per block per K-step into double-buffered LDS; A prefetched one K-step ahead.

template <bool ASPLIT>
__global__ __launch_bounds__(256) void k_gemm(const void* __restrict__ A0,
                                              const void* __restrict__ A1,
                                              const ushort* __restrict__ Whi,
                                              const ushort* __restrict__ Wlo,
                                              const float* __restrict__ bias,
                                              const float* __restrict__ scale,
                                              ushort* __restrict__ Y, int K) {
  __shared__ ushort Bs[2][8192];  // [buf][hi 4096 | lo 4096] = 32 KB
  const int t = threadIdx.x;
  const int w = t >> 6;
  const int l = t & 63;
  const int lr = l & 15;
  const int kg = l >> 4;
  const int r0 = blockIdx.x * 128 + w * 32;
  const int nks = K >> 5;

  f32x4 acc[2][8];
#pragma unroll
  for (int mb = 0; mb < 2; mb++)
#pragma unroll
    for (int nb = 0; nb < 8; nb++) acc[mb][nb] = (f32x4)0.f;

  f32x4 araw[4];
  s16x8 ahn[2], aln[2];
  s16x8 bh0, bh1, bl0, bl1;

  auto issueA = [&](int s) {
#pragma unroll
    for (int mb = 0; mb < 2; mb++) {
      size_t base = (size_t)(r0 + mb * 16 + lr) * K + s * 32 + kg * 8;
      if (ASPLIT) {
        ahn[mb] = *(const s16x8*)((const ushort*)A0 + base);
        aln[mb] = *(const s16x8*)((const ushort*)A1 + base);
      } else {
        const float* xp = (const float*)A0 + base;
        araw[mb * 2] = *(const f32x4*)xp;
        araw[mb * 2 + 1] = *(const f32x4*)(xp + 4);
      }
    }
  };
  auto issueB = [&](int s) {
    const ushort* ph = Whi + (size_t)s * 4096 + t * 16;
    const ushort* pl = Wlo + (size_t)s * 4096 + t * 16;
    bh0 = *(const s16x8*)ph;
    bh1 = *(const s16x8*)(ph + 8);
    bl0 = *(const s16x8*)pl;
    bl1 = *(const s16x8*)(pl + 8);
  };
  auto writeB = [&](int buf) {
    *(s16x8*)&Bs[buf][t * 16] = bh0;
    *(s16x8*)&Bs[buf][t * 16 + 8] = bh1;
    *(s16x8*)&Bs[buf][4096 + t * 16] = bl0;
    *(s16x8*)&Bs[buf][4096 + t * 16 + 8] = bl1;
  };

  issueB(0);
  issueA(0);
  writeB(0);
  __syncthreads();

  int buf = 0;
  for (int s = 0; s < nks; ++s) {
    s16x8 ah[2], al[2];
    if (ASPLIT) {
      ah[0] = ahn[0]; ah[1] = ahn[1];
      al[0] = aln[0]; al[1] = aln[1];
    } else {
#pragma unroll
      for (int mb = 0; mb < 2; mb++) {
        float xv[8] = {araw[mb*2].x, araw[mb*2].y, araw[mb*2].z, araw[mb*2].w,
                       araw[mb*2+1].x, araw[mb*2+1].y, araw[mb*2+1].z, araw[mb*2+1].w};
        union { ushort u[8]; s16x8 v; } H, L;
#pragma unroll
        for (int e = 0; e < 8; e++) {
          ushort h = f2bf(xv[e]);
          H.u[e] = h;
          L.u[e] = f2bf(xv[e] - bf2f(h));
        }
        ah[mb] = H.v;
        al[mb] = L.v;
      }
    }
    const bool more = (s + 1 < nks);
    if (more) { issueB(s + 1); issueA(s + 1); }

#pragma unroll
    for (int nb = 0; nb < 8; nb++) {
      s16x8 bh = *(const s16x8*)&Bs[buf][nb * 512 + l * 8];
      s16x8 bl = *(const s16x8*)&Bs[buf][4096 + nb * 512 + l * 8];
#pragma unroll
      for (int mb = 0; mb < 2; mb++) {
        acc[mb][nb] = __builtin_amdgcn_mfma_f32_16x16x32_bf16(ah[mb], bh, acc[mb][nb], 0, 0, 0);
        acc[mb][nb] = __builtin_amdgcn_mfma_f32_16x16x32_bf16(ah[mb], bl, acc[mb][nb], 0, 0, 0);
        acc[mb][nb] = __builtin_amdgcn_mfma_f32_16x16x32_bf16(al[mb], bh, acc[mb][nb], 0, 0, 0);
      }
    }
    if (more) {
      writeB(buf ^ 1);
      __syncthreads();
      buf ^= 1;
    }
  }

  float dvr[2][4];
#pragma unroll
  for (int mb = 0; mb < 2; mb++)
#pragma unroll
    for (int r = 0; r < 4; r++)
      dvr[mb][r] = scale ? scale[r0 + mb * 16 + kg * 4 + r] : 1.f;

#pragma unroll
  for (int nb = 0; nb < 8; nb++) {
    int col = nb * 16 + lr;
    float bv = bias ? bias[col] : 0.f;
#pragma unroll
    for (int mb = 0; mb < 2; mb++)
#pragma unroll
      for (int r = 0; r < 4; r++) {
        size_t row = (size_t)(r0 + mb * 16 + kg * 4 + r);
        Y[row * FD + col] = f2bf((acc[mb][nb][r] + bv) * dvr[mb][r]);
      }
  }
}

// ---------------- GCN aggregation: wave-per-node, UNIFORM 8-deep pipeline ------
// (round-11/12 proven) Table t = dinv*h, bf16 [NN+1][128] (row NN = zeros).
// out[d] = relu( dinv[d]*(sum_e t[src_e] + t[d]) + b )
// EMIT=0: write hi/lo bf16 planes. EMIT=1: fused segment-max pooling.

template <int EMIT>
__global__ __launch_bounds__(256) void k_agg(const ushort* __restrict__ h16,
                                             const uint* __restrict__ ec,
                                             const int* __restrict__ offs,
                                             const int* __restrict__ hist,
                                             const float* __restrict__ dinv,
                                             const float* __restrict__ bias,
                                             ushort* __restrict__ yhi,
                                             ushort* __restrict__ ylo,
                                             float* __restrict__ pooled) {
  __shared__ int pmax[128];
  const int t = threadIdx.x;
  if (EMIT == 1) {
    if (t < 128) pmax[t] = 0;
    __syncthreads();
  }
  const int n = blockIdx.x * 4 + (t >> 6);
  const int l = t & 63;
  const int half = l >> 5;
  const int dl = (l & 31) * 4;

  const int cnt_p = (hist[n] + 15) & ~15;  // padded count
  const uint* ep = ec + offs[n];

  float a0 = 0.f, a1 = 0.f, a2 = 0.f, a3 = 0.f;
  float b0 = 0.f, b1 = 0.f, b2 = 0.f, b3 = 0.f;
  for (int i = half; i < cnt_p; i += 16) {
    uint s0 = ep[i];
    uint s1 = ep[i + 2];
    uint s2 = ep[i + 4];
    uint s3 = ep[i + 6];
    uint s4 = ep[i + 8];
    uint s5 = ep[i + 10];
    uint s6 = ep[i + 12];
    uint s7 = ep[i + 14];
    ushort4 v0 = *(const ushort4*)(h16 + ((size_t)s0 << 7) + dl);
    ushort4 v1 = *(const ushort4*)(h16 + ((size_t)s1 << 7) + dl);
    ushort4 v2 = *(const ushort4*)(h16 + ((size_t)s2 << 7) + dl);
    ushort4 v3 = *(const ushort4*)(h16 + ((size_t)s3 << 7) + dl);
    ushort4 v4 = *(const ushort4*)(h16 + ((size_t)s4 << 7) + dl);
    ushort4 v5 = *(const ushort4*)(h16 + ((size_t)s5 << 7) + dl);
    ushort4 v6 = *(const ushort4*)(h16 + ((size_t)s6 << 7) + dl);
    ushort4 v7 = *(const ushort4*)(h16 + ((size_t)s7 << 7) + dl);
    a0 += bf2f(v0.x); a1 += bf2f(v0.y); a2 += bf2f(v0.z); a3 += bf2f(v0.w);
    b0 += bf2f(v1.x); b1 += bf2f(v1.y); b2 += bf2f(v1.z); b3 += bf2f(v1.w);
    a0 += bf2f(v2.x); a1 += bf2f(v2.y); a2 += bf2f(v2.z); a3 += bf2f(v2.w);
    b0 += bf2f(v3.x); b1 += bf2f(v3.y); b2 += bf2f(v3.z); b3 += bf2f(v3.w);
    a0 += bf2f(v4.x); a1 += bf2f(v4.y); a2 += bf2f(v4.z); a3 += bf2f(v4.w);
    b0 += bf2f(v5.x); b1 += bf2f(v5.y); b2 += bf2f(v5.z); b3 += bf2f(v5.w);
    a0 += bf2f(v6.x); a1 += bf2f(v6.y); a2 += bf2f(v6.z); a3 += bf2f(v6.w);
    b0 += bf2f(v7.x); b1 += bf2f(v7.y); b2 += bf2f(v7.z); b3 += bf2f(v7.w);
  }
  a0 += b0; a1 += b1; a2 += b2; a3 += b3;
  a0 += __shfl_xor(a0, 32);
  a1 += __shfl_xor(a1, 32);
  a2 += __shfl_xor(a2, 32);
  a3 += __shfl_xor(a3, 32);

  if (l < 32) {
    float dv = dinv[n];
    ushort4 vs = *(const ushort4*)(h16 + ((size_t)n << 7) + dl);  // t[d]
    float4 bb = *(const float4*)(bias + dl);
    float o0 = fmaxf(fmaf(dv, a0 + bf2f(vs.x), bb.x), 0.f);
    float o1 = fmaxf(fmaf(dv, a1 + bf2f(vs.y), bb.y), 0.f);
    float o2 = fmaxf(fmaf(dv, a2 + bf2f(vs.z), bb.z), 0.f);
    float o3 = fmaxf(fmaf(dv, a3 + bf2f(vs.w), bb.w), 0.f);
    if (EMIT == 0) {
      ushort4 hi, lo;
      hi.x = f2bf(o0); lo.x = f2bf(o0 - bf2f(hi.x));
      hi.y = f2bf(o1); lo.y = f2bf(o1 - bf2f(hi.y));
      hi.z = f2bf(o2); lo.z = f2bf(o2 - bf2f(hi.z));
      hi.w = f2bf(o3); lo.w = f2bf(o3 - bf2f(hi.w));
      size_t base = (size_t)n * FD + dl;
      *(ushort4*)(yhi + base) = hi;
      *(ushort4*)(ylo + base) = lo;
    } else {
      // relu>=0: int-compare == float-compare for non-negative floats
      atomicMax(&pmax[dl + 0], __float_as_int(o0));
      atomicMax(&pmax[dl + 1], __float_as_int(o1));
      atomicMax(&pmax[dl + 2], __float_as_int(o2));
      atomicMax(&pmax[dl + 3], __float_as_int(o3));
    }
  }
  if (EMIT == 1) {
    __syncthreads();
    if (t < 128) {
      int gr = blockIdx.x >> 6;  // 64 blocks (256 nodes) per graph
      atomicMax((int*)pooled + gr * FD + t, pmax[t]);
    }
  }
}

// ---------------- MLP head ----------------

__global__ __launch_bounds__(128) void k_mlp(const float* __restrict__ pooled,
                                             const float* __restrict__ Wp1,
                                             const float* __restrict__ bp1,
                                             const float* __restrict__ Wp2,
                                             const float* __restrict__ bp2,
                                             float* __restrict__ out) {
  __shared__ float row[128];
  __shared__ float red[128];
  int g = blockIdx.x, t = threadIdx.x;
  row[t] = pooled[g * FD + t];
  __syncthreads();
  float acc = bp1[t];
#pragma unroll 8
  for (int k = 0; k < 128; k++) acc = fmaf(row[k], Wp1[k * FD + t], acc);
  acc = fmaxf(acc, 0.f);
  red[t] = acc * Wp2[t];
  __syncthreads();
  for (int st = 64; st > 0; st >>= 1) {
    if (t < st) red[t] += red[t + st];
    __syncthreads();
  }
  if (t == 0) out[g] = red[0] + bp2[0];
}

// ---------------- launch ----------------

extern "C" void kernel_launch(void* const* d_in, const int* in_sizes, int n_in,
                              void* d_out, int out_size, void* d_ws, size_t ws_size,
                              hipStream_t stream) {
  (void)in_sizes; (void)n_in; (void)out_size; (void)ws_size;

  const float* adj  = (const float*)d_in[0];
  const int*   edges= (const int*)d_in[1];
  const float* Wdec = (const float*)d_in[3];
  const float* bdec = (const float*)d_in[4];
  const float* Wc1  = (const float*)d_in[5];
  const float* bc1  = (const float*)d_in[6];
  const float* Wc2  = (const float*)d_in[7];
  const float* bc2  = (const float*)d_in[8];
  const float* Wp1  = (const float*)d_in[9];
  const float* bp1  = (const float*)d_in[10];
  const float* Wp2  = (const float*)d_in[11];
  const float* bp2  = (const float*)d_in[12];
  float* out = (float*)d_out;

  char* ws = (char*)d_ws;
  size_t off = 0;
  auto alloc = [&](size_t bytes) -> void* {
    void* p = ws + off;
    off += (bytes + 255) & ~(size_t)255;
    return p;
  };
  ushort* h16  = (ushort*)alloc((size_t)(NN + 1) * FD * 2);  // +1 zero row
  ushort* x1hi = (ushort*)alloc((size_t)NN * FD * 2);
  ushort* x1lo = (ushort*)alloc((size_t)NN * FD * 2);
  // pooled | gbin contiguous -> single memset
  float*  pooled = (float*)alloc((size_t)NGRAPH * FD * 4);
  int*    gbin = (int*)alloc(256 * 4);
  int*    hist = (int*)alloc((size_t)NN * 4);
  int*    offs = (int*)alloc((size_t)NN * 4);
  uint*   ec   = (uint*)alloc((size_t)256 * BCAPP * 4);   // 8.7 MB fixed windows
  uint*   binbuf = (uint*)alloc((size_t)256 * BCAP * 4);  // 4.7 MB bucket bins
  float*  dinv = (float*)alloc((size_t)NN * 4);
  float*  bfused = (float*)alloc(FD * 4);
  ushort* wfh = (ushort*)alloc((size_t)KDEC * FD * 2);
  ushort* wfl = (ushort*)alloc((size_t)KDEC * FD * 2);
  ushort* w2h = (ushort*)alloc((size_t)FD * FD * 2);
  ushort* w2l = (ushort*)alloc((size_t)FD * FD * 2);

  hipMemsetAsync(pooled, 0, (size_t)NGRAPH * FD * 4 + 256 * 4, stream);
  hipMemsetAsync(h16 + (size_t)NN * FD, 0, FD * 2, stream);  // zero row (dummy target)

  // binning + Wfused compute&split + Wc2 split (parallel block roles)
  k_histbin<<<304, 1024, 0, stream>>>(edges, binbuf, gbin, Wdec, Wc1, bdec,
                                      bfused, wfh, wfl, Wc2, w2h, w2l);
  // bucket-local CSR: count -> local scan -> offs/hist/dinv -> scatter -> pad
  k_misc<<<256, 256, 0, stream>>>(binbuf, gbin, hist, offs, dinv, ec);

  // t1 = dinv * (adj @ Wfused + bfused) -> bf16 table
  k_gemm<false><<<NN / 128, 256, 0, stream>>>(adj, nullptr, wfh, wfl, bfused, dinv, h16, KDEC);

  // x1 = relu(dinv*(sum t1 + t1_self) + bc1) -> hi/lo planes
  k_agg<0><<<NN / 4, 256, 0, stream>>>(h16, ec, offs, hist, dinv, bc1, x1hi, x1lo, nullptr);

  // t2 = dinv * (x1 @ Wc2) -> bf16 table
  k_gemm<true><<<NN / 128, 256, 0, stream>>>(x1hi, x1lo, w2h, w2l, nullptr, dinv, h16, FD);

  // pooled = segmax(relu(dinv*(sum t2 + t2_self) + bc2)) fused
  k_agg<1><<<NN / 4, 256, 0, stream>>>(h16, ec, offs, hist, dinv, bc2, nullptr, nullptr, pooled);

  // MLP head
  k_mlp<<<NGRAPH, 128, 0, stream>>>(pooled, Wp1, bp1, Wp2, bp2, out);
}